// Round 11
// baseline (851.823 us; speedup 1.0000x reference)
//
#include <hip/hip_runtime.h>
#include <stdint.h>

#define HDIM 2048
#define NC   12
#define NL   32
#define NBLK 256     // EXACTLY 256 blocks (1/CU) — proven-launchable config
#define NTHR 512     // 8 waves/block; wave (blk*8+wv) owns h-position j
#define NWAVE 8
#define SPINCAP 2000000          // bounded spin: bug => wrong answer, not hang

// ---------------- Threefry-2x32 (20 rounds), JAX partitionable path (verified r4) ----
__device__ __forceinline__ uint32_t rotl32(uint32_t x, int r) {
  return (x << r) | (x >> (32 - r));
}
__device__ __forceinline__ void tf2x32(uint32_t k0, uint32_t k1,
                                       uint32_t &x0, uint32_t &x1) {
  const uint32_t ks2 = k0 ^ k1 ^ 0x1BD11BDAu;
  x0 += k0; x1 += k1;
#define TFR(r) { x0 += x1; x1 = rotl32(x1, (r)); x1 ^= x0; }
  TFR(13) TFR(15) TFR(26) TFR(6)   x0 += k1;  x1 += ks2 + 1u;
  TFR(17) TFR(29) TFR(16) TFR(24)  x0 += ks2; x1 += k0  + 2u;
  TFR(13) TFR(15) TFR(26) TFR(6)   x0 += k0;  x1 += k1  + 3u;
  TFR(17) TFR(29) TFR(16) TFR(24)  x0 += k1;  x1 += ks2 + 4u;
  TFR(13) TFR(15) TFR(26) TFR(6)   x0 += ks2; x1 += k0  + 5u;
#undef TFR
}

// relaxed agent-scope atomics (device-coherent per access, no cache-wide maintenance)
__device__ __forceinline__ uint32_t ald32(const uint32_t* p) {
  return __hip_atomic_load(p, __ATOMIC_RELAXED, __HIP_MEMORY_SCOPE_AGENT);
}
__device__ __forceinline__ float aldf(const float* p) {
  return __uint_as_float(__hip_atomic_load((const uint32_t*)p, __ATOMIC_RELAXED, __HIP_MEMORY_SCOPE_AGENT));
}
__device__ __forceinline__ void astf(float* p, float v) {
  __hip_atomic_store((uint32_t*)p, __float_as_uint(v), __ATOMIC_RELAXED, __HIP_MEMORY_SCOPE_AGENT);
}
__device__ __forceinline__ void ast8(uint8_t* p, uint8_t v) {
  __hip_atomic_store(p, v, __ATOMIC_RELAXED, __HIP_MEMORY_SCOPE_AGENT);
}
#define VMCNT0() asm volatile("s_waitcnt vmcnt(0)" ::: "memory")
#define CFENCE() asm volatile("" ::: "memory")

// ws layout: hb float[2][HDIM] (16 KB) | flags8 uint8[NL][NBLK] (8 KB).
// flags8[t][b]=1 means block b's h(t) words are at the coherence point (vmcnt-ordered).
// Poison 0xAA never equals 0x01. All sync bytes written once per launch.
__global__ void __launch_bounds__(NTHR, 2) ctrl_kernel(
    const float* __restrict__ prev_c, const float* __restrict__ prev_h,
    const float* __restrict__ encoder, const float* __restrict__ w_ih,
    const float* __restrict__ w_hh, const float* __restrict__ b_ih,
    const float* __restrict__ b_hh, const float* __restrict__ w_soft,
    float* __restrict__ out, float* __restrict__ ws)
{
  const int tid  = threadIdx.x;
  const int lane = tid & 63;
  const int wv   = tid >> 6;
  const int blk  = blockIdx.x;
  const int j    = blk * NWAVE + wv;                   // owned h-position

  float*   hbF    = ws;                                // [2][HDIM]
  uint8_t* flags8 = (uint8_t*)(ws + 2 * HDIM);         // [NL][NBLK]

  __shared__ __align__(16) float s_h[HDIM];
  __shared__ float s_E[NWAVE][4][NC];
  __shared__ float s_dot[16];
  __shared__ float s_hnew[NWAVE];
  __shared__ int   s_op;

  if (tid < 16) s_dot[tid] = 0.f;

  // one-time E[c][g] = encoder[c] . w_ih_row(g,j) + b_ih + b_hh  (w_ih read exactly once)
  {
    float4 wif[4][8];
    #pragma unroll
    for (int g = 0; g < 4; ++g) {
      const float4* wp = reinterpret_cast<const float4*>(w_ih + (size_t)(g * HDIM + j) * HDIM);
      #pragma unroll
      for (int k = 0; k < 8; ++k) wif[g][k] = wp[k * 64 + lane];
    }
    float bsum[4];
    #pragma unroll
    for (int g = 0; g < 4; ++g) bsum[g] = b_ih[g * HDIM + j] + b_hh[g * HDIM + j];

    for (int c = 0; c < NC; ++c) {
      const float4* ep = reinterpret_cast<const float4*>(encoder + (size_t)c * HDIM);
      float s0 = 0.f, s1 = 0.f, s2 = 0.f, s3 = 0.f;
      #pragma unroll
      for (int k = 0; k < 8; ++k) {
        float4 e = ep[k * 64 + lane];
        s0 += wif[0][k].x*e.x + wif[0][k].y*e.y + wif[0][k].z*e.z + wif[0][k].w*e.w;
        s1 += wif[1][k].x*e.x + wif[1][k].y*e.y + wif[1][k].z*e.z + wif[1][k].w*e.w;
        s2 += wif[2][k].x*e.x + wif[2][k].y*e.y + wif[2][k].z*e.z + wif[2][k].w*e.w;
        s3 += wif[3][k].x*e.x + wif[3][k].y*e.y + wif[3][k].z*e.z + wif[3][k].w*e.w;
      }
      #pragma unroll
      for (int d = 1; d < 64; d <<= 1) {
        s0 += __shfl_xor(s0, d, 64); s1 += __shfl_xor(s1, d, 64);
        s2 += __shfl_xor(s2, d, 64); s3 += __shfl_xor(s3, d, 64);
      }
      if (lane == 0) {
        s_E[wv][0][c] = s0 + bsum[0]; s_E[wv][1][c] = s1 + bsum[1];
        s_E[wv][2][c] = s2 + bsum[2]; s_E[wv][3][c] = s3 + bsum[3];
      }
    }
  }
  __syncthreads();

  float c_val   = prev_c[j];
  float nll_acc = 0.f, ent_acc = 0.f;                  // meaningful in blk0/wv0/lane0 only

  for (int t = 0; t <= NL; ++t) {
    // ---- A: readiness (wv0 polls 4 flag lines, sleep-paced) + stage h(t-1) ----
    if (t == 0) {
      reinterpret_cast<float4*>(s_h)[tid] = reinterpret_cast<const float4*>(prev_h)[tid];
    } else {
      if (wv == 0) {
        const uint32_t* fw = (const uint32_t*)(flags8 + (size_t)(t - 1) * NBLK);
        for (int it = 0; it < SPINCAP; ++it) {
          uint32_t w = ald32(fw + lane);               // 64 lanes x 4 bytes = whole flag set
          if (__all(w == 0x01010101u)) break;
          __builtin_amdgcn_s_sleep(8);                 // ~0.3us pacing: kill the poll storm
        }
        CFENCE();
      }
      __syncthreads();                                 // other waves held until flags confirmed
      {
        const float* base = hbF + ((t - 1) & 1) * HDIM + wv * 256;
        float v0 = aldf(base + lane),       v1 = aldf(base + lane + 64),
              v2 = aldf(base + lane + 128), v3 = aldf(base + lane + 192);
        s_h[wv * 256 + lane]       = v0;
        s_h[wv * 256 + lane + 64]  = v1;
        s_h[wv * 256 + lane + 128] = v2;
        s_h[wv * 256 + lane + 192] = v3;
      }
    }
    __syncthreads();

    // ---- B: block-local logits of h(t-1): dot[c] = s_h . w_soft[c] (w_soft L2-cached) ----
    if (t > 0) {
      const int c0 = wv, c1 = wv + 8;
      const float4* sh4 = reinterpret_cast<const float4*>(s_h);
      const float4* wsA = reinterpret_cast<const float4*>(w_soft + (size_t)c0 * HDIM);
      const float4* wsB = reinterpret_cast<const float4*>(w_soft + (size_t)(c1 < NC ? c1 : 0) * HDIM);
      float d0 = 0.f, d1 = 0.f;
      #pragma unroll
      for (int k = 0; k < 8; ++k) {
        float4 h4 = sh4[k * 64 + lane];
        float4 a  = wsA[k * 64 + lane];
        d0 += a.x*h4.x + a.y*h4.y + a.z*h4.z + a.w*h4.w;
        if (c1 < NC) {
          float4 b = wsB[k * 64 + lane];
          d1 += b.x*h4.x + b.y*h4.y + b.z*h4.z + b.w*h4.w;
        }
      }
      #pragma unroll
      for (int d = 1; d < 64; d <<= 1) {
        d0 += __shfl_xor(d0, d, 64);
        d1 += __shfl_xor(d1, d, 64);
      }
      if (lane == 0) {
        s_dot[c0] = d0;
        if (c1 < NC) s_dot[c1] = d1;
      }
    }
    __syncthreads();

    // ---- C: replicated sampler on wv0 (bit-identical in every block => identical op);
    //         wv1..7 proceed straight to the GEMV, hiding the sampling cost ----
    if (t > 0 && wv == 0) {
      const int tt = t - 1;
      const float logit = (lane < NC) ? 2.5f * tanhf(s_dot[lane] * 0.2f) : 0.f;

      uint32_t k0, k1, bits;
      { uint32_t a = 0u, b = (uint32_t)tt;   tf2x32(0u, 42u, a, b); k0 = a; k1 = b; }
      { uint32_t a = 0u, b = (uint32_t)lane; tf2x32(k0, k1, a, b); bits = a ^ b; }
      const float TINY = 1.175494350822287508e-38f;
      float f01 = __uint_as_float((bits >> 9) | 0x3f800000u) - 1.0f;
      float u = f01 * (1.0f - TINY) + TINY;
      u = fmaxf(TINY, u);
      const float gmb = -logf(-logf(u));

      float by = (lane < NC) ? (logit + gmb) : -1e30f;
      int   bi = (lane < NC) ? lane : 999;
      #pragma unroll
      for (int d = 1; d < 16; d <<= 1) {
        float oy = __shfl_xor(by, d, 16);
        int   oi = __shfl_xor(bi, d, 16);
        if (oy > by || (oy == by && oi < bi)) { by = oy; bi = oi; }
      }
      const int op = bi;

      if (blk == 0) {                                  // only block 0 writes outputs
        float m = (lane < NC) ? logit : -1e30f;
        #pragma unroll
        for (int d = 1; d < 16; d <<= 1) m = fmaxf(m, __shfl_xor(m, d, 16));
        const float sh = logit - m;
        float S = (lane < NC) ? expf(sh) : 0.f;
        #pragma unroll
        for (int d = 1; d < 16; d <<= 1) S += __shfl_xor(S, d, 16);
        const float lp = sh - logf(S);
        const float lp_op = __shfl(lp, op, 16);
        float tm = (lane < NC) ? expf(lp) * lp : 0.f;
        #pragma unroll
        for (int d = 1; d < 16; d <<= 1) tm += __shfl_xor(tm, d, 16);
        if (lane == 0) {
          out[tt] = (float)op + 0.002f;   // sentinel: 11.000=>never ran; k.002=>sync bug
          nll_acc += -lp_op;
          ent_acc += -tm;
          if (t == NL) { out[NL] = nll_acc; out[NL + 1] = ent_acc; }
        }
      }
      if (lane == 0) s_op = op;
    }
    if (t == NL) break;                                // epilogue iteration: sample(31) only

    // ---- D: w_hh GEMV rows {j, H+j, 2H+j, 3H+j} (plain cached loads — L2-warm slice) ----
    float4 hf[8];
    #pragma unroll
    for (int k = 0; k < 8; ++k) hf[k] = reinterpret_cast<const float4*>(s_h)[k * 64 + lane];
    float gate[4];
    #pragma unroll
    for (int g = 0; g < 4; ++g) {
      const float4* wp = reinterpret_cast<const float4*>(w_hh + (size_t)(g * HDIM + j) * HDIM);
      float s = 0.f;
      #pragma unroll
      for (int k = 0; k < 8; ++k) {
        float4 b = wp[k * 64 + lane];
        s += b.x*hf[k].x + b.y*hf[k].y + b.z*hf[k].z + b.w*hf[k].w;
      }
      #pragma unroll
      for (int d = 1; d < 64; d <<= 1) s += __shfl_xor(s, d, 64);
      gate[g] = s;
    }
    __syncthreads();                                   // s_op (written in C) now visible

    // ---- E: LSTM cell + coalesced publish (one 32B line-write per block) + flag ----
    const int c_idx = (t == 0) ? 0 : ((s_op + 1 > NC - 1) ? NC - 1 : s_op + 1);

    const float iv = 1.f / (1.f + expf(-(gate[0] + s_E[wv][0][c_idx])));
    const float fv = 1.f / (1.f + expf(-(gate[1] + s_E[wv][1][c_idx])));
    const float gv = tanhf(gate[2] + s_E[wv][2][c_idx]);
    const float ov = 1.f / (1.f + expf(-(gate[3] + s_E[wv][3][c_idx])));
    c_val = fv * c_val + iv * gv;
    const float h_new = ov * tanhf(c_val);

    if (lane == 0) s_hnew[wv] = h_new;
    __syncthreads();
    if (wv == 0) {
      if (lane < NWAVE) astf(hbF + (t & 1) * HDIM + blk * NWAVE + lane, s_hnew[lane]);
      VMCNT0();                                        // h words at coherence point...
      if (lane == 0) ast8(flags8 + (size_t)t * NBLK + blk, (uint8_t)1);  // ...then flag
    }
  }
}

extern "C" void kernel_launch(void* const* d_in, const int* in_sizes, int n_in,
                              void* d_out, int out_size, void* d_ws, size_t ws_size,
                              hipStream_t stream) {
  const float* prev_c  = (const float*)d_in[0];
  const float* prev_h  = (const float*)d_in[1];
  const float* encoder = (const float*)d_in[2];
  const float* w_ih    = (const float*)d_in[3];
  const float* w_hh    = (const float*)d_in[4];
  const float* b_ih    = (const float*)d_in[5];
  const float* b_hh    = (const float*)d_in[6];
  const float* w_soft  = (const float*)d_in[7];
  float* out = (float*)d_out;
  float* ws  = (float*)d_ws;   // 24 KB used (h double-buffer + byte flags)

  void* args[] = {&prev_c, &prev_h, &encoder, &w_ih, &w_hh, &b_ih, &b_hh, &w_soft, &out, &ws};
  hipError_t e = hipLaunchCooperativeKernel(reinterpret_cast<void*>(ctrl_kernel),
                                            dim3(NBLK), dim3(NTHR), args, 0, stream);
  if (e != hipSuccess) {
    // 256 blocks @ 1/CU are hardware-co-resident even without the cooperative API;
    // no grid.sync is used — flag protocol only — so plain launch is a valid fallback.
    ctrl_kernel<<<dim3(NBLK), dim3(NTHR), 0, stream>>>(prev_c, prev_h, encoder, w_ih, w_hh,
                                                       b_ih, b_hh, w_soft, out, ws);
  }
}